// Round 12
// baseline (193.489 us; speedup 1.0000x reference)
//
#include <hip/hip_runtime.h>
#include <stdint.h>

#define N_NODES 50000
#define N_EDGES 800000
#define D 128
#define CAP 64      // max in-degree supported; Poisson(16) -> P(>=64) ~ 1e-20
#define NBLK 782    // ceil(50000/64) -> 64 rows per 256-thread block
#define NT2 (NBLK * 256)   // 200192 threads; x4 edges = 800768 >= N_EDGES

typedef __attribute__((ext_vector_type(8))) short short8;
typedef __attribute__((ext_vector_type(4))) float f32x4;

__device__ __forceinline__ unsigned short f2bf(float f) {   // RNE f32->bf16
    uint32_t u = __float_as_uint(f);
    u += 0x7FFFu + ((u >> 16) & 1u);
    return (unsigned short)(u >> 16);
}

// ---------------------------------------------------------------------------
// convert_w: W1|W2 -> bf16 (64 KB, stays L2-resident for gemm_fill) + cnt=0.
// 196 blocks x 256 = 50176 threads.
// ---------------------------------------------------------------------------
__global__ __launch_bounds__(256) void convert_w(const float* __restrict__ W1,
                                                 const float* __restrict__ W2,
                                                 unsigned short* __restrict__ wbf,
                                                 int* __restrict__ cnt)
{
    int gid = blockIdx.x * 256 + threadIdx.x;
    if (gid < N_NODES) cnt[gid] = 0;
    if (gid < 8192) {   // 32768 floats = 8192 float4 (W1: 0..4095, W2: 4096..8191)
        const float* src = (gid < 4096) ? W1 : W2;
        int i = (gid < 4096) ? gid : gid - 4096;
        float4 v = ((const float4*)src)[i];
        unsigned short p0 = f2bf(v.x), p1 = f2bf(v.y), p2 = f2bf(v.z), p3 = f2bf(v.w);
        uint32_t lo = (uint32_t)p0 | ((uint32_t)p1 << 16);
        uint32_t hi = (uint32_t)p2 | ((uint32_t)p3 << 16);
        ((uint2*)wbf)[gid] = make_uint2(lo, hi);
    }
}

// ---------------------------------------------------------------------------
// gemm_fill v2: LDS-free, barrier-free.
//   out = x@W1^T (fp32), hbf = rowL2norm(x@W2^T) (bf16),
//   PLUS edge-bucket build: atomics issued FIRST, consumed in the epilogue,
//   so the ~53us TCC RMW floor hides under the gemm work with no barrier in
//   the way and ~2x the occupancy of the LDS version (104KB -> 0KB).
// Deg-normalization cancels under row L2-norm (positive scalar).
// A-frags: converted in-register from global x (32 fp32/thread, read once).
// B-frags: from 64KB L2-resident wbf (reuse factor 391 per line).
// MFMA 16x16x32: A row=lane&15, k=(lane>>4)*8+j ; C/D col=lane&15,
// row=(lane>>4)*4+reg  [m89-verified layout; r8/r11-passed absmax 0.031]
// ---------------------------------------------------------------------------
__global__ __launch_bounds__(256) void gemm_fill(const float* __restrict__ x,
                                                 const unsigned short* __restrict__ wbf,
                                                 const int* __restrict__ ei,
                                                 float* __restrict__ out,
                                                 unsigned short* __restrict__ hbf,
                                                 int* __restrict__ cnt,
                                                 unsigned short* __restrict__ bucket)
{
    const int t   = threadIdx.x;
    const int gid = blockIdx.x * 256 + t;

    // ---- edge pairs + immediate atomic issue (results used only at end) ----
    int es[4], ed[4], ep[4];
    #pragma unroll
    for (int k = 0; k < 4; ++k) {
        int e = gid + k * NT2;
        bool v = (e < N_EDGES);
        es[k] = v ? ei[e] : 0;
        ed[k] = v ? ei[N_EDGES + e] : -1;
    }
    #pragma unroll
    for (int k = 0; k < 4; ++k)
        ep[k] = (ed[k] >= 0) ? atomicAdd(&cnt[ed[k]], 1) : CAP;

    // ---- A fragments: load this thread's row slice, convert in-register ----
    const int wave = t >> 6;
    const int lane = t & 63;
    const int g    = lane >> 4;      // k-group / row-quad group
    const int ln   = lane & 15;
    const int rowbase = blockIdx.x * 64 + wave * 16;

    int arow  = rowbase + ln;
    int arowc = (arow < N_NODES) ? arow : (N_NODES - 1);  // clamp; stores guarded
    short8 afrag[4];
    #pragma unroll
    for (int ks = 0; ks < 4; ++ks) {
        const float* ap = x + (size_t)arowc * D + ks * 32 + g * 8;
        float4 v0 = *(const float4*)ap;
        float4 v1 = *(const float4*)(ap + 4);
        short8 a;
        a[0] = (short)f2bf(v0.x); a[1] = (short)f2bf(v0.y);
        a[2] = (short)f2bf(v0.z); a[3] = (short)f2bf(v0.w);
        a[4] = (short)f2bf(v1.x); a[5] = (short)f2bf(v1.y);
        a[6] = (short)f2bf(v1.z); a[7] = (short)f2bf(v1.w);
        afrag[ks] = a;
    }

    // ---- dual MFMA: B-frags straight from L2-resident wbf ----
    const unsigned short* w1bf = wbf;
    const unsigned short* w2bf = wbf + 16384;
    f32x4 acc1[8], acc2[8];
    #pragma unroll
    for (int ct = 0; ct < 8; ++ct) {
        f32x4 a1 = {0.f, 0.f, 0.f, 0.f}, a2 = {0.f, 0.f, 0.f, 0.f};
        #pragma unroll
        for (int ks = 0; ks < 4; ++ks) {
            short8 b1 = *(const short8*)&w1bf[(ct * 16 + ln) * D + ks * 32 + g * 8];
            short8 b2 = *(const short8*)&w2bf[(ct * 16 + ln) * D + ks * 32 + g * 8];
            a1 = __builtin_amdgcn_mfma_f32_16x16x32_bf16(afrag[ks], b1, a1, 0, 0, 0);
            a2 = __builtin_amdgcn_mfma_f32_16x16x32_bf16(afrag[ks], b2, a2, 0, 0, 0);
        }
        acc1[ct] = a1; acc2[ct] = a2;
    }

    // ---- fused row-L2-normalize of the W2 half ----
    float ss[4] = {0.f, 0.f, 0.f, 0.f};
    #pragma unroll
    for (int ct = 0; ct < 8; ++ct)
        #pragma unroll
        for (int r = 0; r < 4; ++r)
            ss[r] = fmaf(acc2[ct][r], acc2[ct][r], ss[r]);
    #pragma unroll
    for (int r = 0; r < 4; ++r)
        #pragma unroll
        for (int o = 1; o < 16; o <<= 1)
            ss[r] += __shfl_xor(ss[r], o, 64);
    float scale[4];
    #pragma unroll
    for (int r = 0; r < 4; ++r)
        scale[r] = 1.0f / fmaxf(sqrtf(ss[r]), 1e-12f);

    #pragma unroll
    for (int r = 0; r < 4; ++r) {
        int grow = rowbase + g * 4 + r;
        if (grow < N_NODES) {
            #pragma unroll
            for (int ct = 0; ct < 8; ++ct) {
                out[(size_t)grow * D + ct * 16 + ln] = acc1[ct][r];
                hbf[(size_t)grow * D + ct * 16 + ln] = f2bf(acc2[ct][r] * scale[r]);
            }
        }
    }

    // ---- epilogue: consume atomic results, write 2B bucket entries ----
    #pragma unroll
    for (int k = 0; k < 4; ++k)
        if (ed[k] >= 0 && ep[k] < CAP)
            bucket[ed[k] * CAP + ep[k]] = (unsigned short)es[k];
}

// ---------------------------------------------------------------------------
// per-dst gather-max over bf16 h rows, fused out += ; 16-deep ILP
// (deg~Poisson(16) -> typically ONE batch of 16 outstanding loads)
// ---------------------------------------------------------------------------
__global__ __launch_bounds__(256) void gather_max(const unsigned short* __restrict__ hbf,
                                                  const int* __restrict__ cnt,
                                                  const unsigned short* __restrict__ bucket,
                                                  float* __restrict__ out)
{
    int wid  = (blockIdx.x * 256 + threadIdx.x) >> 6;
    int lane = threadIdx.x & 63;
    if (wid >= N_NODES) return;
    int deg = cnt[wid];
    deg = (deg > CAP) ? CAP : deg;
    if (deg == 0) return;              // empty segment contributes 0

    const uint32_t* h32 = (const uint32_t*)hbf;   // 64 uints (=128 bf16) per row
    int sl = (lane < deg) ? (int)bucket[wid * CAP + lane] : 0;

    float mx = -INFINITY, my = -INFINITY;         // cols 2*lane, 2*lane+1
    int j = 0;
    for (; j + 16 <= deg; j += 16) {
        uint32_t u[16];
        #pragma unroll
        for (int q = 0; q < 16; ++q) {
            int s = __shfl(sl, j + q, 64);
            u[q] = h32[(size_t)s * 64 + lane];
        }
        #pragma unroll
        for (int q = 0; q < 16; ++q) {
            mx = fmaxf(mx, __uint_as_float(u[q] << 16));
            my = fmaxf(my, __uint_as_float(u[q] & 0xFFFF0000u));
        }
    }
    if (j < deg) {
        int rem = deg - j;             // 1..15
        uint32_t u[15];
        for (int q = 0; q < rem; ++q) {
            int s = __shfl(sl, j + q, 64);
            u[q] = h32[(size_t)s * 64 + lane];
        }
        for (int q = 0; q < rem; ++q) {
            mx = fmaxf(mx, __uint_as_float(u[q] << 16));
            my = fmaxf(my, __uint_as_float(u[q] & 0xFFFF0000u));
        }
    }

    float2* o2 = (float2*)out;
    float2 o = o2[(size_t)wid * 64 + lane];
    o.x += mx; o.y += my;
    o2[(size_t)wid * 64 + lane] = o;
}

extern "C" void kernel_launch(void* const* d_in, const int* in_sizes, int n_in,
                              void* d_out, int out_size, void* d_ws, size_t ws_size,
                              hipStream_t stream)
{
    const float* x  = (const float*)d_in[0];
    const float* W1 = (const float*)d_in[1];
    const float* W2 = (const float*)d_in[2];
    const int*   ei = (const int*)d_in[3];
    float* out = (float*)d_out;

    char* ws = (char*)d_ws;
    unsigned short* hbf    = (unsigned short*)ws;                          // 12.8 MB
    int*            cnt    = (int*)(ws + (size_t)N_NODES * D * 2);         // 200 KB
    unsigned short* bucket = (unsigned short*)(ws + (size_t)N_NODES * D * 2
                                                  + (size_t)N_NODES * 4);  // 6.4 MB
    unsigned short* wbf    = (unsigned short*)(ws + (size_t)N_NODES * D * 2
                                                  + (size_t)N_NODES * 4
                                                  + (size_t)N_NODES * CAP * 2); // 64 KB

    convert_w<<<196, 256, 0, stream>>>(W1, W2, wbf, cnt);
    gemm_fill<<<NBLK, 256, 0, stream>>>(x, wbf, ei, out, hbf, cnt, bucket);
    gather_max<<<(N_NODES * 64 + 255) / 256, 256, 0, stream>>>(hbf, cnt, bucket, out);
}

// Round 13
// 171.957 us; speedup vs baseline: 1.1252x; 1.1252x over previous
//
#include <hip/hip_runtime.h>
#include <stdint.h>

#define N_NODES 50000
#define N_EDGES 800000
#define D 128
#define CAP 64      // max in-degree supported; Poisson(16) -> P(>=64) ~ 1e-20
#define LDK 136     // padded LDS K-stride (bf16 elems): +8 -> 2-way bank alias (free)
#define NBLK 391    // ceil(50000/128)
#define NT_FILL (NBLK * 512)   // 200192 threads; x4 edges = 800768 >= N_EDGES

typedef __attribute__((ext_vector_type(8))) short short8;
typedef __attribute__((ext_vector_type(4))) float f32x4;
typedef __attribute__((ext_vector_type(4))) unsigned short ush4;

__device__ __forceinline__ unsigned short f2bf(float f) {   // RNE f32->bf16
    uint32_t u = __float_as_uint(f);
    u += 0x7FFFu + ((u >> 16) & 1u);
    return (unsigned short)(u >> 16);
}

// ---------------------------------------------------------------------------
// gemm_fill (r11-proven form): out = x@W1^T (fp32), hbf = rowL2norm(x@W2^T)
// (bf16), PLUS edge-bucket build overlapped with the MFMA phase.
// KEY ORDERING INVARIANT (r12 lesson): atomics are issued AFTER the staging
// barrier, and the MFMA phase waits only on lgkmcnt (LDS) — since vmcnt
// retires in order, any vmem wait issued after the atomics would block on
// them; here nothing after the atomics waits on vmcnt until the epilogue
// stores, so the ~53us TCC RMW floor hides under the matrix work.
// Deg-normalization cancels under row L2-norm (positive scalar).
// MFMA 16x16x32: A row=lane&15, k=(lane>>4)*8+j ; C/D col=lane&15,
// row=(lane>>4)*4+reg  [m89-verified layout; r8/r11-passed absmax 0.031]
// ---------------------------------------------------------------------------
__global__ __launch_bounds__(512) void gemm_fill(const float* __restrict__ x,
                                                 const float* __restrict__ W1,
                                                 const float* __restrict__ W2,
                                                 const int* __restrict__ ei,
                                                 float* __restrict__ out,
                                                 unsigned short* __restrict__ hbf,
                                                 int* __restrict__ cnt,
                                                 unsigned short* __restrict__ bucket)
{
    __shared__ unsigned short wsm[256][LDK];  // n 0..127 = W1 rows, 128..255 = W2
    __shared__ unsigned short xs[128][LDK];

    const int t    = threadIdx.x;
    const int row0 = blockIdx.x * 128;
    const int gid  = blockIdx.x * 512 + t;

    // ---- edge pairs: load early (completes during staging) ----
    int es[4], ed[4];
    #pragma unroll
    for (int k = 0; k < 4; ++k) {
        int e = gid + k * NT_FILL;
        bool v = (e < N_EDGES);
        es[k] = v ? ei[e] : 0;
        ed[k] = v ? ei[N_EDGES + e] : -1;
    }

    // ---- stage W1|W2 -> bf16 LDS: 256 rows x 32 float4 ----
    #pragma unroll
    for (int it = 0; it < 16; ++it) {
        int idx = it * 512 + t;
        int n = idx >> 5, c4 = idx & 31;
        const float* Wp = (n < 128) ? (W1 + (size_t)n * D) : (W2 + (size_t)(n - 128) * D);
        float4 v = *(const float4*)(Wp + c4 * 4);
        ush4 p; p[0] = f2bf(v.x); p[1] = f2bf(v.y); p[2] = f2bf(v.z); p[3] = f2bf(v.w);
        *(ush4*)&wsm[n][c4 * 4] = p;
    }
    // ---- stage x tile -> bf16 LDS: 128 rows x 32 float4 (zero-pad OOB) ----
    #pragma unroll
    for (int it = 0; it < 8; ++it) {
        int idx = it * 512 + t;
        int r = idx >> 5, c4 = idx & 31;
        int gr = row0 + r;
        float4 v = make_float4(0.f, 0.f, 0.f, 0.f);
        if (gr < N_NODES) v = *(const float4*)(x + (size_t)gr * D + c4 * 4);
        ush4 p; p[0] = f2bf(v.x); p[1] = f2bf(v.y); p[2] = f2bf(v.z); p[3] = f2bf(v.w);
        *(ush4*)&xs[r][c4 * 4] = p;
    }
    __syncthreads();

    // ---- issue index-atomics NOW; results not read until the epilogue ----
    int ep[4];
    #pragma unroll
    for (int k = 0; k < 4; ++k)
        ep[k] = (ed[k] >= 0) ? atomicAdd(&cnt[ed[k]], 1) : CAP;

    // ---- MFMA phase (LDS-only waits; atomics fly in the background) ----
    const int wave = t >> 6;
    const int lane = t & 63;
    const int g    = lane >> 4;
    const int ln   = lane & 15;

    short8 afrag[4];
    #pragma unroll
    for (int ks = 0; ks < 4; ++ks)
        afrag[ks] = *(const short8*)&xs[wave * 16 + ln][ks * 32 + g * 8];

    f32x4 acc1[8], acc2[8];
    #pragma unroll
    for (int ct = 0; ct < 8; ++ct) {
        f32x4 a1 = {0.f, 0.f, 0.f, 0.f}, a2 = {0.f, 0.f, 0.f, 0.f};
        #pragma unroll
        for (int ks = 0; ks < 4; ++ks) {
            short8 b1 = *(const short8*)&wsm[      ct * 16 + ln][ks * 32 + g * 8];
            short8 b2 = *(const short8*)&wsm[128 + ct * 16 + ln][ks * 32 + g * 8];
            a1 = __builtin_amdgcn_mfma_f32_16x16x32_bf16(afrag[ks], b1, a1, 0, 0, 0);
            a2 = __builtin_amdgcn_mfma_f32_16x16x32_bf16(afrag[ks], b2, a2, 0, 0, 0);
        }
        acc1[ct] = a1; acc2[ct] = a2;
    }

    // ---- fused row-L2-normalize of the W2 half ----
    float ss[4] = {0.f, 0.f, 0.f, 0.f};
    #pragma unroll
    for (int ct = 0; ct < 8; ++ct)
        #pragma unroll
        for (int r = 0; r < 4; ++r)
            ss[r] = fmaf(acc2[ct][r], acc2[ct][r], ss[r]);
    #pragma unroll
    for (int r = 0; r < 4; ++r)
        #pragma unroll
        for (int o = 1; o < 16; o <<= 1)
            ss[r] += __shfl_xor(ss[r], o, 64);
    float scale[4];
    #pragma unroll
    for (int r = 0; r < 4; ++r)
        scale[r] = 1.0f / fmaxf(sqrtf(ss[r]), 1e-12f);

    #pragma unroll
    for (int r = 0; r < 4; ++r) {
        int grow = row0 + wave * 16 + g * 4 + r;
        if (grow < N_NODES) {
            #pragma unroll
            for (int ct = 0; ct < 8; ++ct) {
                out[(size_t)grow * D + ct * 16 + ln] = acc1[ct][r];
                hbf[(size_t)grow * D + ct * 16 + ln] = f2bf(acc2[ct][r] * scale[r]);
            }
        }
    }

    // ---- epilogue: consume atomic results, write 2B bucket entries ----
    #pragma unroll
    for (int k = 0; k < 4; ++k)
        if (ed[k] >= 0 && ep[k] < CAP)
            bucket[ed[k] * CAP + ep[k]] = (unsigned short)es[k];
}

// ---------------------------------------------------------------------------
// per-dst gather-max over bf16 h rows, fused out += ; 16-deep ILP
// (deg~Poisson(16) -> typically ONE batch of 16 outstanding row loads,
//  halving the serial-latency chain vs the 8-deep version)
// ---------------------------------------------------------------------------
__global__ __launch_bounds__(256) void gather_max(const unsigned short* __restrict__ hbf,
                                                  const int* __restrict__ cnt,
                                                  const unsigned short* __restrict__ bucket,
                                                  float* __restrict__ out)
{
    int wid  = (blockIdx.x * 256 + threadIdx.x) >> 6;
    int lane = threadIdx.x & 63;
    if (wid >= N_NODES) return;
    int deg = cnt[wid];
    deg = (deg > CAP) ? CAP : deg;
    if (deg == 0) return;              // empty segment contributes 0

    const uint32_t* h32 = (const uint32_t*)hbf;   // 64 uints (=128 bf16) per row
    int sl = (lane < deg) ? (int)bucket[wid * CAP + lane] : 0;

    float mx = -INFINITY, my = -INFINITY;         // cols 2*lane, 2*lane+1
    int j = 0;
    for (; j + 16 <= deg; j += 16) {
        uint32_t u[16];
        #pragma unroll
        for (int q = 0; q < 16; ++q) {
            int s = __shfl(sl, j + q, 64);
            u[q] = h32[(size_t)s * 64 + lane];
        }
        #pragma unroll
        for (int q = 0; q < 16; ++q) {
            mx = fmaxf(mx, __uint_as_float(u[q] << 16));
            my = fmaxf(my, __uint_as_float(u[q] & 0xFFFF0000u));
        }
    }
    if (j < deg) {
        int rem = deg - j;             // 1..15
        uint32_t u[15];
        for (int q = 0; q < rem; ++q) {
            int s = __shfl(sl, j + q, 64);
            u[q] = h32[(size_t)s * 64 + lane];
        }
        for (int q = 0; q < rem; ++q) {
            mx = fmaxf(mx, __uint_as_float(u[q] << 16));
            my = fmaxf(my, __uint_as_float(u[q] & 0xFFFF0000u));
        }
    }

    float2* o2 = (float2*)out;
    float2 o = o2[(size_t)wid * 64 + lane];
    o.x += mx; o.y += my;
    o2[(size_t)wid * 64 + lane] = o;
}

extern "C" void kernel_launch(void* const* d_in, const int* in_sizes, int n_in,
                              void* d_out, int out_size, void* d_ws, size_t ws_size,
                              hipStream_t stream)
{
    const float* x  = (const float*)d_in[0];
    const float* W1 = (const float*)d_in[1];
    const float* W2 = (const float*)d_in[2];
    const int*   ei = (const int*)d_in[3];
    float* out = (float*)d_out;

    char* ws = (char*)d_ws;
    unsigned short* hbf    = (unsigned short*)ws;                          // 12.8 MB
    int*            cnt    = (int*)(ws + (size_t)N_NODES * D * 2);         // 200 KB
    unsigned short* bucket = (unsigned short*)(ws + (size_t)N_NODES * D * 2
                                                  + (size_t)N_NODES * 4);  // 6.4 MB

    hipMemsetAsync(cnt, 0, (size_t)N_NODES * 4, stream);
    gemm_fill<<<NBLK, 512, 0, stream>>>(x, W1, W2, ei, out, hbf, cnt, bucket);
    gather_max<<<(N_NODES * 64 + 255) / 256, 256, 0, stream>>>(hbf, cnt, bucket, out);
}